// Round 7
// baseline (124.124 us; speedup 1.0000x reference)
//
#include <hip/hip_runtime.h>
#include <stdint.h>

// Geometry fixed by the reference: A bits [4,512,512,32], B bits [512,512,32]
#define BATCH 4
#define MDIM  512
#define KDIM  512
#define NDIM  512
#define ROWS  (BATCH * MDIM)   // 2048 flattened output rows
#define BR    8                // C rows per block (8 accs/thread)
#define BCOLS 256              // C cols per block (1 col/thread)

#define WORDS_A (ROWS * KDIM)        // 1,048,576 decoded fp32 words of A
#define WORDS_B (KDIM * NDIM)        //   262,144 decoded fp32 words of B
#define WORDS_T (WORDS_A + WORDS_B)  // 1,310,720
#define DEC_BLOCKS 2048
#define DEC_WAVES  (DEC_BLOCKS * 4)            // 8192 waves
#define DEC_ITERS  (WORDS_T / (16 * DEC_WAVES))  // 10 (exact)

// Spread 8 bits so bit i lands at position 4*i (exact integer op).
__device__ __forceinline__ uint32_t spread4(uint32_t x) {
    x = (x | (x << 12)) & 0x000F000Fu;
    x = (x | (x << 6))  & 0x03030303u;
    x = (x | (x << 3))  & 0x11111111u;
    return x;
}

// ---------------------------------------------------------------------------
// Decode: pulse bits (float {0,1}, bit0=LSB) -> u32 words, fully coalesced.
// Static trip count (10), 2 KiB/wave/iter via two independent uint4/lane ->
// compiler unrolls, >=4 loads in flight per wave. Bit of v is bit29 of its
// IEEE pattern (1.0f = 0x3F800000). Four __ballot per KiB collect the wave's
// 256 bits; lanes (lane&7)==0 assemble word (lane>>3). Integer-exact.
// ---------------------------------------------------------------------------
__global__ __launch_bounds__(256) void decode_all(const float* __restrict__ Abits,
                                                  const float* __restrict__ Bbits,
                                                  uint32_t* __restrict__ Au,
                                                  uint32_t* __restrict__ Bu) {
    const int lane = threadIdx.x & 63;
    const int waveId = (blockIdx.x * blockDim.x + threadIdx.x) >> 6;
    const int sh = lane & 56;                 // 8*(lane>>3)

#pragma unroll
    for (int i = 0; i < DEC_ITERS; ++i) {
        const int wb = (waveId + i * DEC_WAVES) * 16;   // 16 words per wave-iter
        const float* src;
        uint32_t* dst;
        if (wb < WORDS_A) { src = Abits + (size_t)wb * 32;           dst = Au + wb; }
        else              { src = Bbits + (size_t)(wb - WORDS_A) * 32; dst = Bu + (wb - WORDS_A); }

        uint4 v0 = ((const uint4*)src)[lane];        // first KiB (words 0..7)
        uint4 v1 = ((const uint4*)src)[lane + 64];   // second KiB (words 8..15)

        unsigned long long a0 = __ballot((v0.x >> 29) & 1u);
        unsigned long long a1 = __ballot((v0.y >> 29) & 1u);
        unsigned long long a2 = __ballot((v0.z >> 29) & 1u);
        unsigned long long a3 = __ballot((v0.w >> 29) & 1u);
        unsigned long long b0 = __ballot((v1.x >> 29) & 1u);
        unsigned long long b1 = __ballot((v1.y >> 29) & 1u);
        unsigned long long b2 = __ballot((v1.z >> 29) & 1u);
        unsigned long long b3 = __ballot((v1.w >> 29) & 1u);

        if ((lane & 7) == 0) {
            uint32_t w0 = (spread4((uint32_t)(a0 >> sh) & 0xFFu) << 0)
                        | (spread4((uint32_t)(a1 >> sh) & 0xFFu) << 1)
                        | (spread4((uint32_t)(a2 >> sh) & 0xFFu) << 2)
                        | (spread4((uint32_t)(a3 >> sh) & 0xFFu) << 3);
            uint32_t w1 = (spread4((uint32_t)(b0 >> sh) & 0xFFu) << 0)
                        | (spread4((uint32_t)(b1 >> sh) & 0xFFu) << 1)
                        | (spread4((uint32_t)(b2 >> sh) & 0xFFu) << 2)
                        | (spread4((uint32_t)(b3 >> sh) & 0xFFu) << 3);
            dst[lane >> 3] = w0;
            dst[8 + (lane >> 3)] = w1;
        }
    }
}

// ---------------------------------------------------------------------------
// LDS-free GEMM k-loop (exact np.einsum semantics: per output element, single
// accumulator, k ascending, one FMA per step) + LDS-transposed coalesced
// bit-encode epilogue.
// Block: 8 rows x 256 cols, 256 threads; thread = 1 col, 8 row-accs.
// A loads wave-uniform (scalar path); B loads lane-coalesced, L2-resident
// (256 MB L2 traffic total at BR=8). Epilogue: accs -> 8 KiB LDS, 1 barrier,
// then 256 KiB/block written with consecutive-lane float4 stores.
// ---------------------------------------------------------------------------
__global__ __launch_bounds__(256) void gemm_encode(const float* __restrict__ A,
                                                   const float* __restrict__ B,
                                                   float* __restrict__ outbits) {
    __shared__ uint32_t Us[BR][BCOLS];   // 8 KiB

    const int tid = threadIdx.x;
    const int rowBase = blockIdx.x * BR;
    const int n0 = blockIdx.y * BCOLS;
    const int n = n0 + tid;

    float acc[BR];
#pragma unroll
    for (int r = 0; r < BR; ++r) acc[r] = 0.0f;

    const float* Bcol = B + n;
    const float* Arow = A + (size_t)rowBase * KDIM;

#pragma unroll 4
    for (int k0 = 0; k0 < KDIM; k0 += 4) {
        float b0 = Bcol[(size_t)(k0 + 0) * NDIM];
        float b1 = Bcol[(size_t)(k0 + 1) * NDIM];
        float b2 = Bcol[(size_t)(k0 + 2) * NDIM];
        float b3 = Bcol[(size_t)(k0 + 3) * NDIM];
        float4 a[BR];
#pragma unroll
        for (int r = 0; r < BR; ++r)
            a[r] = *(const float4*)(Arow + (size_t)r * KDIM + k0);
#pragma unroll
        for (int r = 0; r < BR; ++r) {
            acc[r] = __builtin_fmaf(a[r].x, b0, acc[r]);
            acc[r] = __builtin_fmaf(a[r].y, b1, acc[r]);
            acc[r] = __builtin_fmaf(a[r].z, b2, acc[r]);
            acc[r] = __builtin_fmaf(a[r].w, b3, acc[r]);
        }
    }

    // ---- epilogue: transpose through LDS, then coalesced bit stores ----
#pragma unroll
    for (int r = 0; r < BR; ++r) Us[r][tid] = __float_as_uint(acc[r]);
    __syncthreads();

    float* oBase = outbits + ((size_t)rowBase * NDIM + n0) * 32;
    const int b = (tid & 7) * 4;
#pragma unroll
    for (int r = 0; r < BR; ++r) {
        float* o = oBase + (size_t)r * NDIM * 32;
#pragma unroll
        for (int it = 0; it < 8; ++it) {
            uint32_t u = Us[r][it * 32 + (tid >> 3)];   // 8-lane broadcast
            float4 q;
            q.x = (float)((u >> (b + 0)) & 1u);
            q.y = (float)((u >> (b + 1)) & 1u);
            q.z = (float)((u >> (b + 2)) & 1u);
            q.w = (float)((u >> (b + 3)) & 1u);
            *(float4*)(o + it * 1024 + tid * 4) = q;    // lanes contiguous
        }
    }
}

extern "C" void kernel_launch(void* const* d_in, const int* in_sizes, int n_in,
                              void* d_out, int out_size, void* d_ws, size_t ws_size,
                              hipStream_t stream) {
    const float* Abits = (const float*)d_in[0];   // [4,512,512,32] floats {0,1}
    const float* Bbits = (const float*)d_in[1];   // [512,512,32]
    float* out = (float*)d_out;                   // [4,512,512,32]

    // Workspace: A_u32 (4 MiB) | B_u32 (1 MiB)
    uint32_t* A_u = (uint32_t*)d_ws;
    uint32_t* B_u = A_u + WORDS_A;

    decode_all<<<DEC_BLOCKS, 256, 0, stream>>>(Abits, Bbits, A_u, B_u);

    dim3 grid(ROWS / BR, NDIM / BCOLS);           // (256, 2) = 512 blocks
    gemm_encode<<<grid, 256, 0, stream>>>((const float*)A_u, (const float*)B_u, out);
}

// Round 8
// 83.844 us; speedup vs baseline: 1.4804x; 1.4804x over previous
//
#include <hip/hip_runtime.h>
#include <stdint.h>

// Geometry fixed by the reference: A bits [4,512,512,32], B bits [512,512,32]
#define BATCH 4
#define MDIM  512
#define KDIM  512
#define NDIM  512
#define ROWS  (BATCH * MDIM)   // 2048 flattened output rows
#define BR    4                // C rows per block (4 accs/thread) -> 4096 waves
#define BCOLS 256              // C cols per block (1 col/thread)

#define WORDS_A (ROWS * KDIM)        // 1,048,576 decoded fp32 words of A
#define WORDS_B (KDIM * NDIM)        //   262,144 decoded fp32 words of B
#define WORDS_T (WORDS_A + WORDS_B)  // 1,310,720
#define DEC_BLOCKS 2048
#define DEC_WAVES  (DEC_BLOCKS * 4)              // 8192 waves
#define DEC_ITERS  (WORDS_T / (32 * DEC_WAVES))  // 5 (exact)

// Spread 8 bits so bit i lands at position 4*i (exact integer op).
__device__ __forceinline__ uint32_t spread4(uint32_t x) {
    x = (x | (x << 12)) & 0x000F000Fu;
    x = (x | (x << 6))  & 0x03030303u;
    x = (x | (x << 3))  & 0x11111111u;
    return x;
}

// ---------------------------------------------------------------------------
// Decode: pulse bits (float {0,1}, bit0=LSB) -> u32 words, fully coalesced.
// Static trip count (5), 4 KiB/wave/iter via four independent uint4/lane ->
// >=8 loads in flight per wave after unroll. Bit of v is bit29 of its IEEE
// pattern (1.0f = 0x3F800000). Four __ballot per KiB collect the wave's
// 256 bits; lanes (lane&7)==0 assemble 4 words each. Integer-exact.
// ---------------------------------------------------------------------------
__global__ __launch_bounds__(256) void decode_all(const float* __restrict__ Abits,
                                                  const float* __restrict__ Bbits,
                                                  uint32_t* __restrict__ Au,
                                                  uint32_t* __restrict__ Bu) {
    const int lane = threadIdx.x & 63;
    const int waveId = (blockIdx.x * blockDim.x + threadIdx.x) >> 6;
    const int sh = lane & 56;                 // 8*(lane>>3)

#pragma unroll
    for (int i = 0; i < DEC_ITERS; ++i) {
        const int wb = (waveId + i * DEC_WAVES) * 32;   // 32 words per wave-iter
        const float* src;
        uint32_t* dst;
        if (wb < WORDS_A) { src = Abits + (size_t)wb * 32;             dst = Au + wb; }
        else              { src = Bbits + (size_t)(wb - WORDS_A) * 32; dst = Bu + (wb - WORDS_A); }

        uint4 v0 = ((const uint4*)src)[lane];         // KiB 0: words  0..7
        uint4 v1 = ((const uint4*)src)[lane + 64];    // KiB 1: words  8..15
        uint4 v2 = ((const uint4*)src)[lane + 128];   // KiB 2: words 16..23
        uint4 v3 = ((const uint4*)src)[lane + 192];   // KiB 3: words 24..31

        unsigned long long m[16];
        m[0]  = __ballot((v0.x >> 29) & 1u);
        m[1]  = __ballot((v0.y >> 29) & 1u);
        m[2]  = __ballot((v0.z >> 29) & 1u);
        m[3]  = __ballot((v0.w >> 29) & 1u);
        m[4]  = __ballot((v1.x >> 29) & 1u);
        m[5]  = __ballot((v1.y >> 29) & 1u);
        m[6]  = __ballot((v1.z >> 29) & 1u);
        m[7]  = __ballot((v1.w >> 29) & 1u);
        m[8]  = __ballot((v2.x >> 29) & 1u);
        m[9]  = __ballot((v2.y >> 29) & 1u);
        m[10] = __ballot((v2.z >> 29) & 1u);
        m[11] = __ballot((v2.w >> 29) & 1u);
        m[12] = __ballot((v3.x >> 29) & 1u);
        m[13] = __ballot((v3.y >> 29) & 1u);
        m[14] = __ballot((v3.z >> 29) & 1u);
        m[15] = __ballot((v3.w >> 29) & 1u);

        if ((lane & 7) == 0) {
#pragma unroll
            for (int g = 0; g < 4; ++g) {
                uint32_t w = (spread4((uint32_t)(m[4*g+0] >> sh) & 0xFFu) << 0)
                           | (spread4((uint32_t)(m[4*g+1] >> sh) & 0xFFu) << 1)
                           | (spread4((uint32_t)(m[4*g+2] >> sh) & 0xFFu) << 2)
                           | (spread4((uint32_t)(m[4*g+3] >> sh) & 0xFFu) << 3);
                dst[8 * g + (lane >> 3)] = w;
            }
        }
    }
}

// ---------------------------------------------------------------------------
// LDS-free GEMM k-loop (exact np.einsum semantics: per output element, single
// accumulator, k ascending, one FMA per step) + LDS-transposed coalesced
// bit-encode epilogue.
// Block: 4 rows x 256 cols, 256 threads; thread = 1 col, 4 row-accs.
// A loads wave-uniform (scalar path); B loads lane-coalesced & L2-resident,
// with EXPLICIT register prefetch one 8-k group ahead (8 loads in flight per
// wave x 4 waves/SIMD hides L2 latency under FMA issue).
// Epilogue: accs -> 4 KiB LDS, 1 barrier, then 128 KiB/block written with
// consecutive-lane float4 stores (wave-contiguous).
// ---------------------------------------------------------------------------
__global__ __launch_bounds__(256) void gemm_encode(const float* __restrict__ A,
                                                   const float* __restrict__ B,
                                                   float* __restrict__ outbits) {
    __shared__ uint32_t Us[BR][BCOLS];   // 4 KiB

    const int tid = threadIdx.x;
    const int rowBase = blockIdx.x * BR;
    const int n0 = blockIdx.y * BCOLS;
    const int n = n0 + tid;

    float acc[BR];
#pragma unroll
    for (int r = 0; r < BR; ++r) acc[r] = 0.0f;

    const float* Bcol = B + n;
    const float* Arow = A + (size_t)rowBase * KDIM;

    float bn[8], bc[8];
#pragma unroll
    for (int i = 0; i < 8; ++i) bn[i] = Bcol[(size_t)i * NDIM];   // prologue

#pragma unroll 2
    for (int k0 = 0; k0 < KDIM; k0 += 8) {
#pragma unroll
        for (int i = 0; i < 8; ++i) bc[i] = bn[i];
        const int kp = (k0 + 8) & (KDIM - 1);    // wraps on last iter (harmless)
#pragma unroll
        for (int i = 0; i < 8; ++i) bn[i] = Bcol[(size_t)(kp + i) * NDIM];

        float4 a0[BR], a1[BR];
#pragma unroll
        for (int r = 0; r < BR; ++r) {
            a0[r] = *(const float4*)(Arow + (size_t)r * KDIM + k0);
            a1[r] = *(const float4*)(Arow + (size_t)r * KDIM + k0 + 4);
        }
        // k ascending per element; one FMA per step.
#pragma unroll
        for (int r = 0; r < BR; ++r) {
            acc[r] = __builtin_fmaf(a0[r].x, bc[0], acc[r]);
            acc[r] = __builtin_fmaf(a0[r].y, bc[1], acc[r]);
            acc[r] = __builtin_fmaf(a0[r].z, bc[2], acc[r]);
            acc[r] = __builtin_fmaf(a0[r].w, bc[3], acc[r]);
            acc[r] = __builtin_fmaf(a1[r].x, bc[4], acc[r]);
            acc[r] = __builtin_fmaf(a1[r].y, bc[5], acc[r]);
            acc[r] = __builtin_fmaf(a1[r].z, bc[6], acc[r]);
            acc[r] = __builtin_fmaf(a1[r].w, bc[7], acc[r]);
        }
    }

    // ---- epilogue: transpose through LDS, then coalesced bit stores ----
#pragma unroll
    for (int r = 0; r < BR; ++r) Us[r][tid] = __float_as_uint(acc[r]);
    __syncthreads();

    float* oBase = outbits + ((size_t)rowBase * NDIM + n0) * 32;
    const int b = (tid & 7) * 4;
#pragma unroll
    for (int r = 0; r < BR; ++r) {
        float* o = oBase + (size_t)r * NDIM * 32;
#pragma unroll
        for (int it = 0; it < 8; ++it) {
            uint32_t u = Us[r][it * 32 + (tid >> 3)];   // 8-lane broadcast
            float4 q;
            q.x = (float)((u >> (b + 0)) & 1u);
            q.y = (float)((u >> (b + 1)) & 1u);
            q.z = (float)((u >> (b + 2)) & 1u);
            q.w = (float)((u >> (b + 3)) & 1u);
            *(float4*)(o + it * 1024 + tid * 4) = q;    // lanes contiguous
        }
    }
}

extern "C" void kernel_launch(void* const* d_in, const int* in_sizes, int n_in,
                              void* d_out, int out_size, void* d_ws, size_t ws_size,
                              hipStream_t stream) {
    const float* Abits = (const float*)d_in[0];   // [4,512,512,32] floats {0,1}
    const float* Bbits = (const float*)d_in[1];   // [512,512,32]
    float* out = (float*)d_out;                   // [4,512,512,32]

    // Workspace: A_u32 (4 MiB) | B_u32 (1 MiB)
    uint32_t* A_u = (uint32_t*)d_ws;
    uint32_t* B_u = A_u + WORDS_A;

    decode_all<<<DEC_BLOCKS, 256, 0, stream>>>(Abits, Bbits, A_u, B_u);

    dim3 grid(ROWS / BR, NDIM / BCOLS);           // (512, 2) = 1024 blocks
    gemm_encode<<<grid, 256, 0, stream>>>((const float*)A_u, (const float*)B_u, out);
}

// Round 9
// 82.862 us; speedup vs baseline: 1.4980x; 1.0119x over previous
//
#include <hip/hip_runtime.h>
#include <stdint.h>

// Geometry fixed by the reference: A bits [4,512,512,32], B bits [512,512,32]
#define BATCH 4
#define MDIM  512
#define KDIM  512
#define NDIM  512
#define ROWS  (BATCH * MDIM)   // 2048 flattened output rows
#define BR    4                // C rows per block
#define THREADS 512            // 8 waves; 1 col/thread

#define WORDS_B (KDIM * NDIM)  // 262,144 decoded fp32 words of B

// Spread 8 bits so bit i lands at position 4*i (exact integer op).
__device__ __forceinline__ uint32_t spread4(uint32_t x) {
    x = (x | (x << 12)) & 0x000F000Fu;
    x = (x | (x << 6))  & 0x03030303u;
    x = (x | (x << 3))  & 0x11111111u;
    return x;
}

// ---------------------------------------------------------------------------
// Decode B: pulse bits -> u32 words, fully coalesced, 4 KiB/wave (32 words),
// exactly one iteration per wave (262144 = 32 * 8192 waves). Bit of v is
// bit29 of its IEEE pattern (1.0f = 0x3F800000). Integer-exact.
// ---------------------------------------------------------------------------
__global__ __launch_bounds__(256) void decode_B(const float* __restrict__ Bbits,
                                                uint32_t* __restrict__ Bu) {
    const int lane = threadIdx.x & 63;
    const int waveId = (blockIdx.x * blockDim.x + threadIdx.x) >> 6;
    const int sh = lane & 56;                 // 8*(lane>>3)

    const int wb = waveId * 32;               // 32 words per wave
    const float* src = Bbits + (size_t)wb * 32;
    uint32_t* dst = Bu + wb;

    uint4 v0 = ((const uint4*)src)[lane];
    uint4 v1 = ((const uint4*)src)[lane + 64];
    uint4 v2 = ((const uint4*)src)[lane + 128];
    uint4 v3 = ((const uint4*)src)[lane + 192];

    unsigned long long m[16];
    m[0]  = __ballot((v0.x >> 29) & 1u);  m[1]  = __ballot((v0.y >> 29) & 1u);
    m[2]  = __ballot((v0.z >> 29) & 1u);  m[3]  = __ballot((v0.w >> 29) & 1u);
    m[4]  = __ballot((v1.x >> 29) & 1u);  m[5]  = __ballot((v1.y >> 29) & 1u);
    m[6]  = __ballot((v1.z >> 29) & 1u);  m[7]  = __ballot((v1.w >> 29) & 1u);
    m[8]  = __ballot((v2.x >> 29) & 1u);  m[9]  = __ballot((v2.y >> 29) & 1u);
    m[10] = __ballot((v2.z >> 29) & 1u);  m[11] = __ballot((v2.w >> 29) & 1u);
    m[12] = __ballot((v3.x >> 29) & 1u);  m[13] = __ballot((v3.y >> 29) & 1u);
    m[14] = __ballot((v3.z >> 29) & 1u);  m[15] = __ballot((v3.w >> 29) & 1u);

    if ((lane & 7) == 0) {
#pragma unroll
        for (int q = 0; q < 4; ++q) {
            uint32_t w = (spread4((uint32_t)(m[4*q+0] >> sh) & 0xFFu) << 0)
                       | (spread4((uint32_t)(m[4*q+1] >> sh) & 0xFFu) << 1)
                       | (spread4((uint32_t)(m[4*q+2] >> sh) & 0xFFu) << 2)
                       | (spread4((uint32_t)(m[4*q+3] >> sh) & 0xFFu) << 3);
            dst[8 * q + (lane >> 3)] = w;
        }
    }
}

// ---------------------------------------------------------------------------
// Fused kernel: A-panel ballot-decode -> LDS, strict-order GEMM k-loop
// (per output element: single accumulator, k ascending, one FMA per step),
// LDS-transposed coalesced bit-encode epilogue. One block = 4 rows x 512
// cols, 512 threads (8 waves), 1 col/thread, 4 accs.
//   Phase 1: 256 KB contiguous A-bits -> 2048 u32 words in 8 KB LDS
//            (wave-coalesced uint4 loads + ballots; exact integer ops).
//   Phase 2: A via uniform LDS float4 broadcast; B lane-coalesced from
//            L2-resident B_u with 8-deep register prefetch.
//   Phase 3: reuse the same LDS for acc transpose; wave-contiguous float4
//            bit stores (256 KB/block).
// ---------------------------------------------------------------------------
__global__ __launch_bounds__(THREADS) void gemm_fused(const float* __restrict__ Abits,
                                                      const float* __restrict__ Bu,
                                                      float* __restrict__ outbits) {
    __shared__ uint32_t AsU[BR][KDIM];   // 8 KiB, reused by epilogue

    const int tid  = threadIdx.x;
    const int lane = tid & 63;
    const int wv   = tid >> 6;           // wave 0..7
    const int rowBase = blockIdx.x * BR;
    const int sh = lane & 56;

    // ---- Phase 1: decode own A panel (words [BR][KDIM], row-major) ----
    const float* panel = Abits + (size_t)rowBase * KDIM * 32;
#pragma unroll
    for (int i = 0; i < 8; ++i) {
        const float* src = panel + wv * 8192 + i * 1024;   // 4 KiB/wave/iter
        uint4 v0 = ((const uint4*)src)[lane];
        uint4 v1 = ((const uint4*)src)[lane + 64];
        uint4 v2 = ((const uint4*)src)[lane + 128];
        uint4 v3 = ((const uint4*)src)[lane + 192];

        unsigned long long m[16];
        m[0]  = __ballot((v0.x >> 29) & 1u);  m[1]  = __ballot((v0.y >> 29) & 1u);
        m[2]  = __ballot((v0.z >> 29) & 1u);  m[3]  = __ballot((v0.w >> 29) & 1u);
        m[4]  = __ballot((v1.x >> 29) & 1u);  m[5]  = __ballot((v1.y >> 29) & 1u);
        m[6]  = __ballot((v1.z >> 29) & 1u);  m[7]  = __ballot((v1.w >> 29) & 1u);
        m[8]  = __ballot((v2.x >> 29) & 1u);  m[9]  = __ballot((v2.y >> 29) & 1u);
        m[10] = __ballot((v2.z >> 29) & 1u);  m[11] = __ballot((v2.w >> 29) & 1u);
        m[12] = __ballot((v3.x >> 29) & 1u);  m[13] = __ballot((v3.y >> 29) & 1u);
        m[14] = __ballot((v3.z >> 29) & 1u);  m[15] = __ballot((v3.w >> 29) & 1u);

        if ((lane & 7) == 0) {
#pragma unroll
            for (int q = 0; q < 4; ++q) {
                uint32_t w = (spread4((uint32_t)(m[4*q+0] >> sh) & 0xFFu) << 0)
                           | (spread4((uint32_t)(m[4*q+1] >> sh) & 0xFFu) << 1)
                           | (spread4((uint32_t)(m[4*q+2] >> sh) & 0xFFu) << 2)
                           | (spread4((uint32_t)(m[4*q+3] >> sh) & 0xFFu) << 3);
                int wi = wv * 256 + i * 32 + q * 8 + (lane >> 3);  // panel word
                AsU[wi >> 9][wi & (KDIM - 1)] = w;
            }
        }
    }
    __syncthreads();

    // ---- Phase 2: strict-order k-loop ----
    float acc[BR];
#pragma unroll
    for (int r = 0; r < BR; ++r) acc[r] = 0.0f;

    const float* Bcol = (const float*)Bu + tid;        // col n = tid
    const float* Asf = (const float*)&AsU[0][0];

    float bn[8], bc[8];
#pragma unroll
    for (int i = 0; i < 8; ++i) bn[i] = Bcol[(size_t)i * NDIM];

#pragma unroll 2
    for (int k0 = 0; k0 < KDIM; k0 += 8) {
#pragma unroll
        for (int i = 0; i < 8; ++i) bc[i] = bn[i];
        const int kp = (k0 + 8) & (KDIM - 1);          // wraps last iter (harmless)
#pragma unroll
        for (int i = 0; i < 8; ++i) bn[i] = Bcol[(size_t)(kp + i) * NDIM];

        float4 a0[BR], a1[BR];
#pragma unroll
        for (int r = 0; r < BR; ++r) {
            a0[r] = *(const float4*)(Asf + r * KDIM + k0);      // uniform LDS
            a1[r] = *(const float4*)(Asf + r * KDIM + k0 + 4);  // broadcast
        }
#pragma unroll
        for (int r = 0; r < BR; ++r) {
            acc[r] = __builtin_fmaf(a0[r].x, bc[0], acc[r]);
            acc[r] = __builtin_fmaf(a0[r].y, bc[1], acc[r]);
            acc[r] = __builtin_fmaf(a0[r].z, bc[2], acc[r]);
            acc[r] = __builtin_fmaf(a0[r].w, bc[3], acc[r]);
            acc[r] = __builtin_fmaf(a1[r].x, bc[4], acc[r]);
            acc[r] = __builtin_fmaf(a1[r].y, bc[5], acc[r]);
            acc[r] = __builtin_fmaf(a1[r].z, bc[6], acc[r]);
            acc[r] = __builtin_fmaf(a1[r].w, bc[7], acc[r]);
        }
    }
    __syncthreads();   // all A reads done; reuse LDS for transpose

    // ---- Phase 3: transpose + coalesced bit stores ----
    uint32_t* Us = &AsU[0][0];   // [BR][512]
#pragma unroll
    for (int r = 0; r < BR; ++r) Us[r * NDIM + tid] = __float_as_uint(acc[r]);
    __syncthreads();

    float* oBase = outbits + (size_t)rowBase * NDIM * 32;
    const int b = (tid & 7) * 4;
#pragma unroll
    for (int r = 0; r < BR; ++r) {
        float* o = oBase + (size_t)r * NDIM * 32;
#pragma unroll
        for (int it = 0; it < 8; ++it) {
            uint32_t u = Us[r * NDIM + it * 64 + (tid >> 3)];   // 8-lane broadcast
            float4 q;
            q.x = (float)((u >> (b + 0)) & 1u);
            q.y = (float)((u >> (b + 1)) & 1u);
            q.z = (float)((u >> (b + 2)) & 1u);
            q.w = (float)((u >> (b + 3)) & 1u);
            *(float4*)(o + it * 2048 + tid * 4) = q;            // lanes contiguous
        }
    }
}

extern "C" void kernel_launch(void* const* d_in, const int* in_sizes, int n_in,
                              void* d_out, int out_size, void* d_ws, size_t ws_size,
                              hipStream_t stream) {
    const float* Abits = (const float*)d_in[0];   // [4,512,512,32] floats {0,1}
    const float* Bbits = (const float*)d_in[1];   // [512,512,32]
    float* out = (float*)d_out;                   // [4,512,512,32]

    // Workspace: B_u32 (1 MiB)
    uint32_t* B_u = (uint32_t*)d_ws;

    decode_B<<<2048, 256, 0, stream>>>(Bbits, B_u);
    gemm_fused<<<ROWS / BR, THREADS, 0, stream>>>(Abits, (const float*)B_u, out);
}